// Round 2
// baseline (489.978 us; speedup 1.0000x reference)
//
#include <hip/hip_runtime.h>

#define T_TOK 2048
#define H_DIM 1024
#define E_NUM 16
#define F_DIM 1024
#define NKB 32  // K tiled in 32 blocks of 32

typedef unsigned short u16;
typedef unsigned int u32;
typedef short s16x8 __attribute__((ext_vector_type(8)));
typedef float f32x4 __attribute__((ext_vector_type(4)));

__device__ __forceinline__ float b2f(u16 v) { return __uint_as_float(((u32)v) << 16); }
__device__ __forceinline__ u16 f2b(float f) {
  u32 u = __float_as_uint(f);
  return (u16)((u + 0x7fffu + ((u >> 16) & 1u)) >> 16);
}

__device__ __forceinline__ void gl_lds16(const u32* g, u32* l) {
  __builtin_amdgcn_global_load_lds((const __attribute__((address_space(1))) void*)g,
                                   (__attribute__((address_space(3))) void*)l, 16, 0, 0);
}

// ---------------- rw transpose: rwT[e][h] = rw[h][e] ----------------
__global__ __launch_bounds__(256) void rw_transpose_kernel(const float* __restrict__ rw,
                                                           float* __restrict__ rwT) {
  int idx = blockIdx.x * 256 + threadIdx.x;  // 16384 elems, grid 64
  float v = rw[idx];
  rwT[(idx & 15) * 1024 + (idx >> 4)] = v;
}

// ---------------- router: coalesced via rwT, logits, top-2, softmax, counts ----------------
__global__ __launch_bounds__(256) void router_kernel(const float* __restrict__ hidden,
                                                     const float* __restrict__ rwT,
                                                     int* __restrict__ counts,
                                                     int* __restrict__ routing_e,
                                                     float* __restrict__ routing_w) {
  int wv = threadIdx.x >> 6, lane = threadIdx.x & 63;
  int t = blockIdx.x * 4 + wv;
  const float* xrow = hidden + (size_t)t * H_DIM;
  float acc[E_NUM];
#pragma unroll
  for (int e = 0; e < E_NUM; ++e) acc[e] = 0.f;
  for (int j = 0; j < H_DIM / 64; ++j) {
    int h = j * 64 + lane;
    float x = xrow[h];
#pragma unroll
    for (int e = 0; e < E_NUM; ++e) acc[e] += x * rwT[e * 1024 + h];
  }
#pragma unroll
  for (int e = 0; e < E_NUM; ++e) {
    acc[e] += __shfl_xor(acc[e], 32, 64);
    acc[e] += __shfl_xor(acc[e], 16, 64);
    acc[e] += __shfl_xor(acc[e], 8, 64);
    acc[e] += __shfl_xor(acc[e], 4, 64);
    acc[e] += __shfl_xor(acc[e], 2, 64);
    acc[e] += __shfl_xor(acc[e], 1, 64);
  }
  if (lane == 0) {
    float v0 = -1e30f, v1 = -1e30f;
    int i0 = 0, i1 = 0;
#pragma unroll
    for (int e = 0; e < E_NUM; ++e) {
      float v = acc[e];
      if (v > v0) { v1 = v0; i1 = i0; v0 = v; i0 = e; }
      else if (v > v1) { v1 = v; i1 = e; }
    }
    float p0 = 1.f / (1.f + __expf(v1 - v0));  // stable: v1 <= v0
    routing_e[2 * t] = i0;
    routing_e[2 * t + 1] = i1;
    routing_w[2 * t] = p0;
    routing_w[2 * t + 1] = 1.f - p0;
    atomicAdd(&counts[i0], 1);
    atomicAdd(&counts[i1], 1);
  }
}

// ---------------- scatter: prefix offsets + slot maps + per-slot weight ----------------
__global__ void scatter_kernel(const int* __restrict__ counts, int* __restrict__ offsets,
                               const int* __restrict__ routing_e, const float* __restrict__ routing_w,
                               int* __restrict__ token_of_slot, float* __restrict__ slot_w) {
  __shared__ int offs[E_NUM];
  __shared__ int cur[E_NUM];
  int tid = threadIdx.x;
  if (tid == 0) {
    int s = 0;
    for (int e = 0; e < E_NUM; ++e) { offs[e] = s; s += counts[e]; }
  }
  __syncthreads();
  if (tid < E_NUM) { offsets[tid] = offs[tid]; cur[tid] = offs[tid]; }
  __syncthreads();
  for (int i = tid; i < 2 * T_TOK; i += 256) {
    int e = routing_e[i];
    int pos = atomicAdd(&cur[e], 1);
    token_of_slot[pos] = i >> 1;
    slot_w[pos] = routing_w[i];
  }
}

// split 8 fp32 -> bf16 hi + bf16 lo(residual), packed for b128 store
__device__ __forceinline__ void split_pack(const float* __restrict__ p, uint4& hh, uint4& ll) {
  u16 h[8], l[8];
#pragma unroll
  for (int i = 0; i < 8; ++i) {
    h[i] = f2b(p[i]);
    l[i] = f2b(p[i] - b2f(h[i]));
  }
  hh.x = (u32)h[0] | ((u32)h[1] << 16);
  hh.y = (u32)h[2] | ((u32)h[3] << 16);
  hh.z = (u32)h[4] | ((u32)h[5] << 16);
  hh.w = (u32)h[6] | ((u32)h[7] << 16);
  ll.x = (u32)l[0] | ((u32)l[1] << 16);
  ll.y = (u32)l[2] | ((u32)l[3] << 16);
  ll.z = (u32)l[4] | ((u32)l[5] << 16);
  ll.w = (u32)l[6] | ((u32)l[7] << 16);
}

// ---------------- prep_x: hidden f32 -> bf16 hi/lo planes ----------------
__global__ __launch_bounds__(256) void prep_x(const float* __restrict__ x, u16* __restrict__ xh,
                                              u16* __restrict__ xl) {
  int i = blockIdx.x * 256 + threadIdx.x;  // 8 elems per thread, exact grid
  float4 a = ((const float4*)x)[2 * i];
  float4 b = ((const float4*)x)[2 * i + 1];
  float v[8] = {a.x, a.y, a.z, a.w, b.x, b.y, b.z, b.w};
  uint4 hh, ll;
  split_pack(v, hh, ll);
  ((uint4*)xh)[i] = hh;
  ((uint4*)xl)[i] = ll;
}

// ---------------- prep_w (LDS-free): f32 [1024][N] -> bf16 swizzled 8KB tiles ----------------
// tile word layout matches read_bfrag: row n, slot (g0 ^ s)&3 (s = ((n>>3)^n)&3) holds
// kp group g0 (kp = g0*4+w, word = bf16(2kp)|bf16(2kp+1)<<16).
__global__ __launch_bounds__(256) void prep_w(const float* __restrict__ w, u32* __restrict__ wt,
                                              int N) {
  const int e = blockIdx.z, nbk = blockIdx.y, kb = blockIdx.x;
  const float* src = w + (size_t)e * 1024 * N + (size_t)kb * 32 * N + nbk * 128;
  u32* dst = wt + (((size_t)e * gridDim.y + nbk) * NKB + kb) * 2048;
  const int t = threadIdx.x;
  const int n = t & 127, h = t >> 7;  // h: k-half (16 k each)
  const int s = ((n >> 3) ^ n) & 3;
  const float* col = src + (size_t)(16 * h) * N + n;
  float v[16];
#pragma unroll
  for (int kk = 0; kk < 16; ++kk) v[kk] = col[(size_t)kk * N];
  __align__(16) u32 wbuf[8];
#pragma unroll
  for (int j = 0; j < 8; ++j) wbuf[j] = (u32)f2b(v[2 * j]) | ((u32)f2b(v[2 * j + 1]) << 16);
  u32* row = dst + n * 16;
  *(uint4*)(row + (((2 * h) ^ s) & 3) * 4) = *(uint4*)&wbuf[0];
  *(uint4*)(row + (((2 * h + 1) ^ s) & 3) * 4) = *(uint4*)&wbuf[4];
}

__device__ __forceinline__ s16x8 read_bfrag(const u32* __restrict__ B, int n, int q) {
  return *(const s16x8*)&B[n * 16 + (((q ^ (n >> 3) ^ n) & 3) << 2)];
}

#define MFMA(a, b, c) __builtin_amdgcn_mfma_f32_16x16x32_bf16(a, b, c, 0, 0, 0)

// ---------------- GEMM1: 4-buffer depth-3 pipeline, counted vmcnt, raw barriers ----------------
__global__ __launch_bounds__(256, 2) void moe_gemm1(
    const u16* __restrict__ Xh, const u16* __restrict__ Xl, const u32* __restrict__ wgu_t,
    const int* __restrict__ token_of_slot, const int* __restrict__ counts,
    const int* __restrict__ offsets, u16* __restrict__ act_h, u16* __restrict__ act_l) {
  const int e = blockIdx.z;
  const int cnt = counts[e];
  const int m0 = blockIdx.y * 64;
  if (m0 >= cnt) return;
  const int off = offsets[e];
  const int xb = blockIdx.x;

  __shared__ u32 Bg[4][2048];
  __shared__ u32 Bu[4][2048];

  const int tid = threadIdx.x;
  const int lane = tid & 63;
  const int wv = tid >> 6;
  const int q = lane >> 4, ln = lane & 15;
  const int mb = (wv & 1) * 32, nb = (wv >> 1) * 64;

  const int r0 = m0 + mb + ln, r1 = r0 + 16;
  const int t0 = (r0 < cnt) ? token_of_slot[off + r0] : 0;
  const int t1 = (r1 < cnt) ? token_of_slot[off + r1] : 0;
  const u16* xh0 = Xh + (size_t)t0 * H_DIM + q * 8;
  const u16* xh1 = Xh + (size_t)t1 * H_DIM + q * 8;
  const u16* xl0 = Xl + (size_t)t0 * H_DIM + q * 8;
  const u16* xl1 = Xl + (size_t)t1 * H_DIM + q * 8;

  const u32* g_g = wgu_t + (((size_t)e * 16 + xb) * NKB) * 2048 + tid * 4;
  const u32* g_u = wgu_t + (((size_t)e * 16 + xb + 8) * NKB) * 2048 + tid * 4;

  f32x4 zero = {0.f, 0.f, 0.f, 0.f};
  f32x4 accg[2][4], accu[2][4];
#pragma unroll
  for (int i = 0; i < 2; ++i)
#pragma unroll
    for (int j = 0; j < 4; ++j) { accg[i][j] = zero; accu[i][j] = zero; }

#define G1STAGE(KBN)                                      \
  {                                                       \
    const int bix = (KBN) & 3;                            \
    const u32* sg = g_g + (size_t)(KBN) * 2048;           \
    const u32* su = g_u + (size_t)(KBN) * 2048;           \
    gl_lds16(sg, &Bg[bix][0] + wv * 256);                 \
    gl_lds16(sg + 1024, &Bg[bix][0] + 1024 + wv * 256);   \
    gl_lds16(su, &Bu[bix][0] + wv * 256);                 \
    gl_lds16(su + 1024, &Bu[bix][0] + 1024 + wv * 256);   \
  }

  s16x8 pH0, pH1, pL0, pL1, qH0, qH1, qL0, qL1;

  // prologue issue order: B0, A0, B1, B2  (depth-3 prefetch)
  G1STAGE(0);
  pH0 = *(const s16x8*)(xh0);
  pH1 = *(const s16x8*)(xh1);
  pL0 = *(const s16x8*)(xl0);
  pL1 = *(const s16x8*)(xl1);
  G1STAGE(1);
  G1STAGE(2);

#define G1BODY(KB, H0, H1, L0, L1, NH0, NH1, NL0, NL1, WN, DOPF, DOST)  \
  {                                                                     \
    if (DOPF) {                                                         \
      const int ko = ((KB) + 1) * 32;                                   \
      NH0 = *(const s16x8*)(xh0 + ko);                                  \
      NH1 = *(const s16x8*)(xh1 + ko);                                  \
      NL0 = *(const s16x8*)(xl0 + ko);                                  \
      NL1 = *(const s16x8*)(xl1 + ko);                                  \
    }                                                                   \
    asm volatile("s_waitcnt vmcnt(" WN ")" ::: "memory");               \
    __builtin_amdgcn_sched_barrier(0);                                  \
    __builtin_amdgcn_s_barrier();                                       \
    __builtin_amdgcn_sched_barrier(0);                                  \
    if (DOST) G1STAGE((KB) + 3);                                        \
    const u32* Bgc = &Bg[(KB) & 3][0];                                  \
    const u32* Buc = &Bu[(KB) & 3][0];                                  \
    __builtin_amdgcn_s_setprio(1);                                      \
    _Pragma("unroll") for (int j = 0; j < 4; ++j) {                     \
      s16x8 bg = read_bfrag(Bgc, nb + j * 16 + ln, q);                  \
      s16x8 bu = read_bfrag(Buc, nb + j * 16 + ln, q);                  \
      accg[0][j] = MFMA(H0, bg, accg[0][j]);                            \
      accg[1][j] = MFMA(H1, bg, accg[1][j]);                            \
      accu[0][j] = MFMA(H0, bu, accu[0][j]);                            \
      accu[1][j] = MFMA(H1, bu, accu[1][j]);                            \
      accg[0][j] = MFMA(L0, bg, accg[0][j]);                            \
      accg[1][j] = MFMA(L1, bg, accg[1][j]);                            \
      accu[0][j] = MFMA(L0, bu, accu[0][j]);                            \
      accu[1][j] = MFMA(L1, bu, accu[1][j]);                            \
    }                                                                   \
    __builtin_amdgcn_s_setprio(0);                                      \
  }

  for (int kb = 0; kb < 28; kb += 2) {
    G1BODY(kb, pH0, pH1, pL0, pL1, qH0, qH1, qL0, qL1, "8", 1, 1);
    G1BODY(kb + 1, qH0, qH1, qL0, qL1, pH0, pH1, pL0, pL1, "8", 1, 1);
  }
  G1BODY(28, pH0, pH1, pL0, pL1, qH0, qH1, qL0, qL1, "8", 1, 1);
  G1BODY(29, qH0, qH1, qL0, qL1, pH0, pH1, pL0, pL1, "8", 1, 0);
  G1BODY(30, pH0, pH1, pL0, pL1, qH0, qH1, qL0, qL1, "4", 1, 0);
  G1BODY(31, qH0, qH1, qL0, qL1, pH0, pH1, pL0, pL1, "0", 0, 0);

  const int bcol = xb * 128 + nb + ln;
#pragma unroll
  for (int i = 0; i < 2; ++i) {
#pragma unroll
    for (int r = 0; r < 4; ++r) {
      int row = mb + i * 16 + q * 4 + r;
      if (m0 + row < cnt) {
        size_t rb = (size_t)(off + m0 + row) * F_DIM + bcol;
#pragma unroll
        for (int j = 0; j < 4; ++j) {
          float g = accg[i][j][r], u = accu[i][j][r];
          float a = g * (1.f / (1.f + __expf(-g))) * u;
          u16 h = f2b(a);
          u16 l = f2b(a - b2f(h));
          act_h[rb + j * 16] = h;
          act_l[rb + j * 16] = l;
        }
      }
    }
  }
}

// ---------------- GEMM2: same pipeline, single B matrix, atomic fp32 out ----------------
__global__ __launch_bounds__(256, 3) void moe_gemm2(
    const u16* __restrict__ Ah, const u16* __restrict__ Al, const u32* __restrict__ wd_t,
    const int* __restrict__ token_of_slot, const float* __restrict__ slot_w,
    const int* __restrict__ counts, const int* __restrict__ offsets,
    float* __restrict__ out) {
  const int e = blockIdx.z;
  const int cnt = counts[e];
  const int m0 = blockIdx.y * 64;
  if (m0 >= cnt) return;
  const int off = offsets[e];
  const int xb = blockIdx.x;

  __shared__ u32 Bd[4][2048];

  const int tid = threadIdx.x;
  const int lane = tid & 63;
  const int wv = tid >> 6;
  const int q = lane >> 4, ln = lane & 15;
  const int mb = (wv & 1) * 32, nb = (wv >> 1) * 64;

  const int r0 = m0 + mb + ln, r1 = r0 + 16;
  const int s0 = off + ((r0 < cnt) ? r0 : 0);
  const int s1 = off + ((r1 < cnt) ? r1 : 0);
  const u16* ah0 = Ah + (size_t)s0 * F_DIM + q * 8;
  const u16* ah1 = Ah + (size_t)s1 * F_DIM + q * 8;
  const u16* al0 = Al + (size_t)s0 * F_DIM + q * 8;
  const u16* al1 = Al + (size_t)s1 * F_DIM + q * 8;

  const u32* g_d = wd_t + (((size_t)e * 8 + xb) * NKB) * 2048 + tid * 4;

  f32x4 zero = {0.f, 0.f, 0.f, 0.f};
  f32x4 acc[2][4];
#pragma unroll
  for (int i = 0; i < 2; ++i)
#pragma unroll
    for (int j = 0; j < 4; ++j) acc[i][j] = zero;

#define G2STAGE(KBN)                                      \
  {                                                       \
    const int bix = (KBN) & 3;                            \
    const u32* sd = g_d + (size_t)(KBN) * 2048;           \
    gl_lds16(sd, &Bd[bix][0] + wv * 256);                 \
    gl_lds16(sd + 1024, &Bd[bix][0] + 1024 + wv * 256);   \
  }

  s16x8 pH0, pH1, pL0, pL1, qH0, qH1, qL0, qL1;

  G2STAGE(0);
  pH0 = *(const s16x8*)(ah0);
  pH1 = *(const s16x8*)(ah1);
  pL0 = *(const s16x8*)(al0);
  pL1 = *(const s16x8*)(al1);
  G2STAGE(1);
  G2STAGE(2);

#define G2BODY(KB, H0, H1, L0, L1, NH0, NH1, NL0, NL1, WN, DOPF, DOST)  \
  {                                                                     \
    if (DOPF) {                                                         \
      const int ko = ((KB) + 1) * 32;                                   \
      NH0 = *(const s16x8*)(ah0 + ko);                                  \
      NH1 = *(const s16x8*)(ah1 + ko);                                  \
      NL0 = *(const s16x8*)(al0 + ko);                                  \
      NL1 = *(const s16x8*)(al1 + ko);                                  \
    }                                                                   \
    asm volatile("s_waitcnt vmcnt(" WN ")" ::: "memory");               \
    __builtin_amdgcn_sched_barrier(0);                                  \
    __builtin_amdgcn_s_barrier();                                       \
    __builtin_amdgcn_sched_barrier(0);                                  \
    if (DOST) G2STAGE((KB) + 3);                                        \
    const u32* Bdc = &Bd[(KB) & 3][0];                                  \
    __builtin_amdgcn_s_setprio(1);                                      \
    _Pragma("unroll") for (int j = 0; j < 4; ++j) {                     \
      s16x8 bf = read_bfrag(Bdc, nb + j * 16 + ln, q);                  \
      acc[0][j] = MFMA(H0, bf, acc[0][j]);                              \
      acc[1][j] = MFMA(H1, bf, acc[1][j]);                              \
      acc[0][j] = MFMA(L0, bf, acc[0][j]);                              \
      acc[1][j] = MFMA(L1, bf, acc[1][j]);                              \
    }                                                                   \
    __builtin_amdgcn_s_setprio(0);                                      \
  }

  for (int kb = 0; kb < 28; kb += 2) {
    G2BODY(kb, pH0, pH1, pL0, pL1, qH0, qH1, qL0, qL1, "6", 1, 1);
    G2BODY(kb + 1, qH0, qH1, qL0, qL1, pH0, pH1, pL0, pL1, "6", 1, 1);
  }
  G2BODY(28, pH0, pH1, pL0, pL1, qH0, qH1, qL0, qL1, "6", 1, 1);
  G2BODY(29, qH0, qH1, qL0, qL1, pH0, pH1, pL0, pL1, "6", 1, 0);
  G2BODY(30, pH0, pH1, pL0, pL1, qH0, qH1, qL0, qL1, "4", 1, 0);
  G2BODY(31, qH0, qH1, qL0, qL1, pH0, pH1, pL0, pL1, "0", 0, 0);

#pragma unroll
  for (int i = 0; i < 2; ++i) {
#pragma unroll
    for (int r = 0; r < 4; ++r) {
      int row = mb + i * 16 + q * 4 + r;
      if (m0 + row < cnt) {
        int slot = off + m0 + row;
        int tok = token_of_slot[slot];
        float wgt = slot_w[slot];
        float* orow = out + (size_t)tok * H_DIM + xb * 128 + nb + ln;
#pragma unroll
        for (int j = 0; j < 4; ++j) atomicAdd(&orow[j * 16], wgt * acc[i][j][r]);
      }
    }
  }
}

extern "C" void kernel_launch(void* const* d_in, const int* in_sizes, int n_in,
                              void* d_out, int out_size, void* d_ws, size_t ws_size,
                              hipStream_t stream) {
  const float* hidden = (const float*)d_in[0];  // [2048][1024] f32
  const float* rw = (const float*)d_in[1];      // [1024][16]   f32
  const float* wgu = (const float*)d_in[2];     // [16][1024][2048] f32
  const float* wd = (const float*)d_in[3];      // [16][1024][1024] f32
  float* out = (float*)d_out;                   // [2048][1024] f32
  char* ws = (char*)d_ws;

  // workspace layout (~126 MB)
  int* counts = (int*)(ws);                        // 64 B
  int* offsets = (int*)(ws + 256);                 // 64 B
  int* routing_e = (int*)(ws + 1024);              // 16 KB
  float* routing_w = (float*)(ws + 17408);         // 16 KB
  int* token_of_slot = (int*)(ws + 33792);         // 16 KB
  float* slot_w = (float*)(ws + 50176);            // 16 KB
  float* rwT = (float*)(ws + 65536);               // 64 KB [16][1024] f32
  u16* Xh = (u16*)(ws + 131072ull);                // 4 MB  [2048][1024] bf16 hi
  u16* Xl = (u16*)(ws + 4325376ull);               // 4 MB  bf16 lo residual
  u16* act_h = (u16*)(ws + 8519680ull);            // 8 MB  [4096][1024] bf16 hi
  u16* act_l = (u16*)(ws + 16908288ull);           // 8 MB  bf16 lo residual
  u32* wgu_t = (u32*)(ws + 25296896ull);           // 64 MB swizzled bf16 tiles
  u32* wd_t  = (u32*)(ws + 92405760ull);           // 32 MB swizzled bf16 tiles

  hipMemsetAsync(counts, 0, 64, stream);
  hipMemsetAsync(out, 0, (size_t)out_size * sizeof(float), stream);
  rw_transpose_kernel<<<dim3(64), dim3(256), 0, stream>>>(rw, rwT);
  router_kernel<<<dim3(T_TOK / 4), dim3(256), 0, stream>>>(hidden, rwT, counts, routing_e,
                                                           routing_w);
  scatter_kernel<<<dim3(1), dim3(256), 0, stream>>>(counts, offsets, routing_e, routing_w,
                                                    token_of_slot, slot_w);
  prep_x<<<dim3(T_TOK * H_DIM / 8 / 256), dim3(256), 0, stream>>>(hidden, Xh, Xl);
  prep_w<<<dim3(NKB, 16, E_NUM), dim3(256), 0, stream>>>(wgu, wgu_t, 2048);
  prep_w<<<dim3(NKB, 8, E_NUM), dim3(256), 0, stream>>>(wd, wd_t, 1024);
  moe_gemm1<<<dim3(8, 32, E_NUM), dim3(256), 0, stream>>>(Xh, Xl, wgu_t, token_of_slot, counts,
                                                          offsets, act_h, act_l);
  moe_gemm2<<<dim3(8, 32, E_NUM), dim3(256), 0, stream>>>(act_h, act_l, wd_t, token_of_slot,
                                                          slot_w, counts, offsets, out);
}

// Round 3
// 425.589 us; speedup vs baseline: 1.1513x; 1.1513x over previous
//
#include <hip/hip_runtime.h>

#define T_TOK 2048
#define H_DIM 1024
#define E_NUM 16
#define F_DIM 1024
#define PNL 256  // slot-panel rows held in accumulators

typedef unsigned short u16;
typedef unsigned int u32;
typedef short s16x8 __attribute__((ext_vector_type(8)));
typedef float f32x4 __attribute__((ext_vector_type(4)));

__device__ __forceinline__ float b2f(u16 v) { return __uint_as_float(((u32)v) << 16); }
__device__ __forceinline__ u16 f2b(float f) {
  u32 u = __float_as_uint(f);
  return (u16)((u + 0x7fffu + ((u >> 16) & 1u)) >> 16);
}

#define BARRIER()                                            \
  do {                                                       \
    asm volatile("s_waitcnt lgkmcnt(0)" ::: "memory");       \
    __builtin_amdgcn_sched_barrier(0);                       \
    __builtin_amdgcn_s_barrier();                            \
    __builtin_amdgcn_sched_barrier(0);                       \
  } while (0)

// ---------------- rw transpose: rwT[e][h] = rw[h][e] ----------------
__global__ __launch_bounds__(256) void rw_transpose_kernel(const float* __restrict__ rw,
                                                           float* __restrict__ rwT) {
  int idx = blockIdx.x * 256 + threadIdx.x;  // 16384 elems, grid 64
  float v = rw[idx];
  rwT[(idx & 15) * 1024 + (idx >> 4)] = v;
}

// ---------------- router: coalesced via rwT, logits, top-2, softmax, counts ----------------
__global__ __launch_bounds__(256) void router_kernel(const float* __restrict__ hidden,
                                                     const float* __restrict__ rwT,
                                                     int* __restrict__ counts,
                                                     int* __restrict__ routing_e,
                                                     float* __restrict__ routing_w) {
  int wv = threadIdx.x >> 6, lane = threadIdx.x & 63;
  int t = blockIdx.x * 4 + wv;
  const float* xrow = hidden + (size_t)t * H_DIM;
  float acc[E_NUM];
#pragma unroll
  for (int e = 0; e < E_NUM; ++e) acc[e] = 0.f;
  for (int j = 0; j < H_DIM / 64; ++j) {
    int h = j * 64 + lane;
    float x = xrow[h];
#pragma unroll
    for (int e = 0; e < E_NUM; ++e) acc[e] += x * rwT[e * 1024 + h];
  }
#pragma unroll
  for (int e = 0; e < E_NUM; ++e) {
    acc[e] += __shfl_xor(acc[e], 32, 64);
    acc[e] += __shfl_xor(acc[e], 16, 64);
    acc[e] += __shfl_xor(acc[e], 8, 64);
    acc[e] += __shfl_xor(acc[e], 4, 64);
    acc[e] += __shfl_xor(acc[e], 2, 64);
    acc[e] += __shfl_xor(acc[e], 1, 64);
  }
  if (lane == 0) {
    float v0 = -1e30f, v1 = -1e30f;
    int i0 = 0, i1 = 0;
#pragma unroll
    for (int e = 0; e < E_NUM; ++e) {
      float v = acc[e];
      if (v > v0) { v1 = v0; i1 = i0; v0 = v; i0 = e; }
      else if (v > v1) { v1 = v; i1 = e; }
    }
    float p0 = 1.f / (1.f + __expf(v1 - v0));  // stable: v1 <= v0
    routing_e[2 * t] = i0;
    routing_e[2 * t + 1] = i1;
    routing_w[2 * t] = p0;
    routing_w[2 * t + 1] = 1.f - p0;
    atomicAdd(&counts[i0], 1);
    atomicAdd(&counts[i1], 1);
  }
}

// ---------------- scatter: prefix offsets + slot maps + per-slot weight ----------------
__global__ void scatter_kernel(const int* __restrict__ counts, int* __restrict__ offsets,
                               const int* __restrict__ routing_e, const float* __restrict__ routing_w,
                               int* __restrict__ token_of_slot, float* __restrict__ slot_w) {
  __shared__ int offs[E_NUM];
  __shared__ int cur[E_NUM];
  int tid = threadIdx.x;
  if (tid == 0) {
    int s = 0;
    for (int e = 0; e < E_NUM; ++e) { offs[e] = s; s += counts[e]; }
  }
  __syncthreads();
  if (tid < E_NUM) { offsets[tid] = offs[tid]; cur[tid] = offs[tid]; }
  __syncthreads();
  for (int i = tid; i < 2 * T_TOK; i += 256) {
    int e = routing_e[i];
    int pos = atomicAdd(&cur[e], 1);
    token_of_slot[pos] = i >> 1;
    slot_w[pos] = routing_w[i];
  }
}

// split 8 fp32 -> bf16 hi + bf16 lo(residual), packed for b128 store
__device__ __forceinline__ void split_pack(const float* __restrict__ p, uint4& hh, uint4& ll) {
  u16 h[8], l[8];
#pragma unroll
  for (int i = 0; i < 8; ++i) {
    h[i] = f2b(p[i]);
    l[i] = f2b(p[i] - b2f(h[i]));
  }
  hh.x = (u32)h[0] | ((u32)h[1] << 16);
  hh.y = (u32)h[2] | ((u32)h[3] << 16);
  hh.z = (u32)h[4] | ((u32)h[5] << 16);
  hh.w = (u32)h[6] | ((u32)h[7] << 16);
  ll.x = (u32)l[0] | ((u32)l[1] << 16);
  ll.y = (u32)l[2] | ((u32)l[3] << 16);
  ll.z = (u32)l[4] | ((u32)l[5] << 16);
  ll.w = (u32)l[6] | ((u32)l[7] << 16);
}

// ---------------- prep_x: hidden f32 -> bf16 hi/lo planes ----------------
__global__ __launch_bounds__(256) void prep_x(const float* __restrict__ x, u16* __restrict__ xh,
                                              u16* __restrict__ xl) {
  int i = blockIdx.x * 256 + threadIdx.x;  // 8 elems per thread, exact grid
  float4 a = ((const float4*)x)[2 * i];
  float4 b = ((const float4*)x)[2 * i + 1];
  float v[8] = {a.x, a.y, a.z, a.w, b.x, b.y, b.z, b.w};
  uint4 hh, ll;
  split_pack(v, hh, ll);
  ((uint4*)xh)[i] = hh;
  ((uint4*)xl)[i] = ll;
}

// B-tile fragment read: [n][16 u32 words], kp-group g0 stored at slot (g0 ^ (n>>3) ^ n)&3
__device__ __forceinline__ s16x8 read_bfrag(const u32* __restrict__ B, int n, int q) {
  return *(const s16x8*)&B[n * 16 + (((q ^ (n >> 3) ^ n) & 3) << 2)];
}

#define MFMA(a, b, c) __builtin_amdgcn_mfma_f32_16x16x32_bf16(a, b, c, 0, 0, 0)

// ==================== GEMM1: act = silu(X@Wg)*(X@Wu) ====================
// grid (16 f-stripes, 16 experts); 512 thr; block owns 64 f-cols (gate+up), streams K once
// per 256-row panel, converting f32 W -> bf16 swizzled LDS tiles in-flight.

#define WLOAD1(P, KK)                                              \
  {                                                                \
    const float* wp_ = wptr + (size_t)(KK) * 65536;                \
    P##0 = wp_[0];     P##1 = wp_[2048];  P##2 = wp_[4096];        \
    P##3 = wp_[6144];  P##4 = wp_[8192];  P##5 = wp_[10240];       \
    P##6 = wp_[12288]; P##7 = wp_[14336];                          \
  }

#define WCVT1(P, WW)                                               \
  {                                                                \
    WW.x = (u32)f2b(P##0) | ((u32)f2b(P##1) << 16);                \
    WW.y = (u32)f2b(P##2) | ((u32)f2b(P##3) << 16);                \
    WW.z = (u32)f2b(P##4) | ((u32)f2b(P##5) << 16);                \
    WW.w = (u32)f2b(P##6) | ((u32)f2b(P##7) << 16);                \
  }

__global__ __launch_bounds__(512, 2) void moe_gemm1(
    const u16* __restrict__ Xh, const u16* __restrict__ Xl, const float* __restrict__ wgu,
    const int* __restrict__ token_of_slot, const int* __restrict__ counts,
    const int* __restrict__ offsets, u16* __restrict__ act_h, u16* __restrict__ act_l) {
  const int e = blockIdx.y;
  const int cnt = counts[e];
  if (cnt == 0) return;
  const int off = offsets[e];
  const int f0 = blockIdx.x * 64;

  __shared__ u32 Bt[2][2048];  // [buf][mat*1024 + n*16 + word]  (gate tile | up tile)

  const int tid = threadIdx.x;
  const int lane = tid & 63;
  const int wv = tid >> 6;  // 0..7
  const int q = lane >> 4, ln = lane & 15;
  const int mb = wv * 32;

  // W gather map: mat=bit8, wh = bit7*2 + bit0, wn = bit6*32 + (lane>>1)
  const int mat = tid >> 8;
  const int wn = ((tid >> 6) & 1) * 32 + ((tid & 63) >> 1);
  const int wh = ((tid >> 7) & 1) * 2 + (tid & 1);
  const float* wptr = wgu + (size_t)e * 2097152 + (size_t)(wh * 8) * 2048 + mat * 1024 + f0 + wn;
  const int wofs = mat * 1024 + wn * 16 + (((wh ^ (wn >> 3) ^ wn) & 3) << 2);

  float wa0, wa1, wa2, wa3, wa4, wa5, wa6, wa7;
  float wb0, wb1, wb2, wb3, wb4, wb5, wb6, wb7;
  s16x8 pH0, pH1, pL0, pL1, qH0, qH1, qL0, qL1;

#define G1IT(KK, PAR, WC, WN, H0, H1, L0, L1, NH0, NH1, NL0, NL1, NOTLAST, DOW) \
  {                                                                             \
    if (NOTLAST) {                                                              \
      const int ko_ = ((KK) + 1) * 32;                                          \
      NH0 = *(const s16x8*)(xh0 + ko_);                                         \
      NH1 = *(const s16x8*)(xh1 + ko_);                                         \
      NL0 = *(const s16x8*)(xl0 + ko_);                                         \
      NL1 = *(const s16x8*)(xl1 + ko_);                                         \
    }                                                                           \
    {                                                                           \
      const u32* Bc_ = &Bt[PAR][0];                                             \
      __builtin_amdgcn_s_setprio(1);                                            \
      _Pragma("unroll") for (int nf = 0; nf < 4; ++nf) {                        \
        s16x8 bg = read_bfrag(Bc_, nf * 16 + ln, q);                            \
        s16x8 bu = read_bfrag(Bc_ + 1024, nf * 16 + ln, q);                     \
        accg[0][nf] = MFMA(H0, bg, accg[0][nf]);                                \
        accg[1][nf] = MFMA(H1, bg, accg[1][nf]);                                \
        accg[0][nf] = MFMA(L0, bg, accg[0][nf]);                                \
        accg[1][nf] = MFMA(L1, bg, accg[1][nf]);                                \
        accu[0][nf] = MFMA(H0, bu, accu[0][nf]);                                \
        accu[1][nf] = MFMA(H1, bu, accu[1][nf]);                                \
        accu[0][nf] = MFMA(L0, bu, accu[0][nf]);                                \
        accu[1][nf] = MFMA(L1, bu, accu[1][nf]);                                \
      }                                                                         \
      __builtin_amdgcn_s_setprio(0);                                            \
    }                                                                           \
    if (NOTLAST) {                                                              \
      uint4 ww_;                                                                \
      WCVT1(WC, ww_);                                                           \
      *(uint4*)&Bt[1 - (PAR)][wofs] = ww_;                                      \
      if (DOW) WLOAD1(WN, (KK) + 2);                                            \
      BARRIER();                                                                \
    }                                                                           \
  }

  for (int p0 = 0; p0 < cnt; p0 += PNL) {
    const int rr0 = p0 + mb + ln, rr1 = rr0 + 16;
    const int t0 = (rr0 < cnt) ? token_of_slot[off + rr0] : 0;
    const int t1 = (rr1 < cnt) ? token_of_slot[off + rr1] : 0;
    const u16* xh0 = Xh + (size_t)t0 * H_DIM + q * 8;
    const u16* xh1 = Xh + (size_t)t1 * H_DIM + q * 8;
    const u16* xl0 = Xl + (size_t)t0 * H_DIM + q * 8;
    const u16* xl1 = Xl + (size_t)t1 * H_DIM + q * 8;

    f32x4 zero = {0.f, 0.f, 0.f, 0.f};
    f32x4 accg[2][4], accu[2][4];
#pragma unroll
    for (int i = 0; i < 2; ++i)
#pragma unroll
      for (int j = 0; j < 4; ++j) { accg[i][j] = zero; accu[i][j] = zero; }

    // prologue: W(0)->wa, A(0)->p, write buf0, W(1)->wb
    WLOAD1(wa, 0);
    pH0 = *(const s16x8*)(xh0);
    pH1 = *(const s16x8*)(xh1);
    pL0 = *(const s16x8*)(xl0);
    pL1 = *(const s16x8*)(xl1);
    {
      uint4 w0_;
      WCVT1(wa, w0_);
      *(uint4*)&Bt[0][wofs] = w0_;
    }
    WLOAD1(wb, 1);
    BARRIER();

    for (int kk = 0; kk < 28; kk += 2) {
      G1IT(kk, 0, wb, wa, pH0, pH1, pL0, pL1, qH0, qH1, qL0, qL1, 1, 1);
      G1IT(kk + 1, 1, wa, wb, qH0, qH1, qL0, qL1, pH0, pH1, pL0, pL1, 1, 1);
    }
    G1IT(28, 0, wb, wa, pH0, pH1, pL0, pL1, qH0, qH1, qL0, qL1, 1, 1);
    G1IT(29, 1, wa, wb, qH0, qH1, qL0, qL1, pH0, pH1, pL0, pL1, 1, 1);
    G1IT(30, 0, wb, wa, pH0, pH1, pL0, pL1, qH0, qH1, qL0, qL1, 1, 0);
    G1IT(31, 1, wa, wb, qH0, qH1, qL0, qL1, pH0, pH1, pL0, pL1, 0, 0);

    // epilogue: silu(g)*u -> act planes
#pragma unroll
    for (int m = 0; m < 2; ++m) {
#pragma unroll
      for (int r = 0; r < 4; ++r) {
        int rl = mb + m * 16 + q * 4 + r;
        int sr = p0 + rl;
        if (sr < cnt) {
          size_t rb = (size_t)(off + sr) * F_DIM + f0 + ln;
#pragma unroll
          for (int nf = 0; nf < 4; ++nf) {
            float g = accg[m][nf][r], u = accu[m][nf][r];
            float a = g * (1.f / (1.f + __expf(-g))) * u;
            u16 hh = f2b(a);
            act_h[rb + nf * 16] = hh;
            act_l[rb + nf * 16] = f2b(a - b2f(hh));
          }
        }
      }
    }
  }
}

// ==================== GEMM2: out[tok,h] += w_slot * (act @ w_down) ====================

#define WLOAD2(P, KK)                                       \
  {                                                         \
    const float* wp_ = wptr2 + (size_t)(KK) * 32768;        \
    P##0 = wp_[0];    P##1 = wp_[1024];                     \
    P##2 = wp_[2048]; P##3 = wp_[3072];                     \
  }

#define WCVT2(P, WW)                                        \
  {                                                         \
    WW.x = (u32)f2b(P##0) | ((u32)f2b(P##1) << 16);         \
    WW.y = (u32)f2b(P##2) | ((u32)f2b(P##3) << 16);         \
  }

__global__ __launch_bounds__(512, 2) void moe_gemm2(
    const u16* __restrict__ Ah, const u16* __restrict__ Al, const float* __restrict__ wd,
    const int* __restrict__ token_of_slot, const float* __restrict__ slot_w,
    const int* __restrict__ counts, const int* __restrict__ offsets,
    float* __restrict__ out) {
  const int e = blockIdx.y;
  const int cnt = counts[e];
  if (cnt == 0) return;
  const int off = offsets[e];
  const int h0 = blockIdx.x * 64;

  __shared__ u32 Bt[2][1024];

  const int tid = threadIdx.x;
  const int lane = tid & 63;
  const int wv = tid >> 6;
  const int q = lane >> 4, ln = lane & 15;
  const int mb = wv * 32;

  // W gather map: n2 = tid&63 (coalesced 256B rows), kpb = tid>>6 (4 k-rows each)
  const int n2 = tid & 63, kpb = tid >> 6;
  const float* wptr2 = wd + (size_t)e * 1048576 + (size_t)(kpb * 4) * 1024 + h0 + n2;
  const int wofs2 = n2 * 16 + ((((kpb >> 1) ^ (n2 >> 3) ^ n2) & 3) << 2) + (kpb & 1) * 2;

  float wa0, wa1, wa2, wa3;
  float wb0, wb1, wb2, wb3;
  s16x8 pH0, pH1, pL0, pL1, qH0, qH1, qL0, qL1;

#define G2IT(KK, PAR, WC, WN, H0, H1, L0, L1, NH0, NH1, NL0, NL1, NOTLAST, DOW) \
  {                                                                             \
    if (NOTLAST) {                                                              \
      const int ko_ = ((KK) + 1) * 32;                                          \
      NH0 = *(const s16x8*)(ah0 + ko_);                                         \
      NH1 = *(const s16x8*)(ah1 + ko_);                                         \
      NL0 = *(const s16x8*)(al0 + ko_);                                         \
      NL1 = *(const s16x8*)(al1 + ko_);                                         \
    }                                                                           \
    {                                                                           \
      const u32* Bc_ = &Bt[PAR][0];                                             \
      __builtin_amdgcn_s_setprio(1);                                            \
      _Pragma("unroll") for (int nf = 0; nf < 4; ++nf) {                        \
        s16x8 bf = read_bfrag(Bc_, nf * 16 + ln, q);                            \
        acc[0][nf] = MFMA(H0, bf, acc[0][nf]);                                  \
        acc[1][nf] = MFMA(H1, bf, acc[1][nf]);                                  \
        acc[0][nf] = MFMA(L0, bf, acc[0][nf]);                                  \
        acc[1][nf] = MFMA(L1, bf, acc[1][nf]);                                  \
      }                                                                         \
      __builtin_amdgcn_s_setprio(0);                                            \
    }                                                                           \
    if (NOTLAST) {                                                              \
      uint2 ww_;                                                                \
      WCVT2(WC, ww_);                                                           \
      *(uint2*)&Bt[1 - (PAR)][wofs2] = ww_;                                     \
      if (DOW) WLOAD2(WN, (KK) + 2);                                            \
      BARRIER();                                                                \
    }                                                                           \
  }

  for (int p0 = 0; p0 < cnt; p0 += PNL) {
    const int rr0 = p0 + mb + ln, rr1 = rr0 + 16;
    const int s0 = off + ((rr0 < cnt) ? rr0 : 0);
    const int s1 = off + ((rr1 < cnt) ? rr1 : 0);
    const u16* ah0 = Ah + (size_t)s0 * F_DIM + q * 8;
    const u16* ah1 = Ah + (size_t)s1 * F_DIM + q * 8;
    const u16* al0 = Al + (size_t)s0 * F_DIM + q * 8;
    const u16* al1 = Al + (size_t)s1 * F_DIM + q * 8;

    f32x4 zero = {0.f, 0.f, 0.f, 0.f};
    f32x4 acc[2][4];
#pragma unroll
    for (int i = 0; i < 2; ++i)
#pragma unroll
      for (int j = 0; j < 4; ++j) acc[i][j] = zero;

    WLOAD2(wa, 0);
    pH0 = *(const s16x8*)(ah0);
    pH1 = *(const s16x8*)(ah1);
    pL0 = *(const s16x8*)(al0);
    pL1 = *(const s16x8*)(al1);
    {
      uint2 w0_;
      WCVT2(wa, w0_);
      *(uint2*)&Bt[0][wofs2] = w0_;
    }
    WLOAD2(wb, 1);
    BARRIER();

    for (int kk = 0; kk < 28; kk += 2) {
      G2IT(kk, 0, wb, wa, pH0, pH1, pL0, pL1, qH0, qH1, qL0, qL1, 1, 1);
      G2IT(kk + 1, 1, wa, wb, qH0, qH1, qL0, qL1, pH0, pH1, pL0, pL1, 1, 1);
    }
    G2IT(28, 0, wb, wa, pH0, pH1, pL0, pL1, qH0, qH1, qL0, qL1, 1, 1);
    G2IT(29, 1, wa, wb, qH0, qH1, qL0, qL1, pH0, pH1, pL0, pL1, 1, 1);
    G2IT(30, 0, wb, wa, pH0, pH1, pL0, pL1, qH0, qH1, qL0, qL1, 1, 0);
    G2IT(31, 1, wa, wb, qH0, qH1, qL0, qL1, pH0, pH1, pL0, pL1, 0, 0);

#pragma unroll
    for (int m = 0; m < 2; ++m) {
#pragma unroll
      for (int r = 0; r < 4; ++r) {
        int rl = mb + m * 16 + q * 4 + r;
        int sr = p0 + rl;
        if (sr < cnt) {
          int slot = off + sr;
          int tok = token_of_slot[slot];
          float wgt = slot_w[slot];
          float* orow = out + (size_t)tok * H_DIM + h0 + ln;
#pragma unroll
          for (int nf = 0; nf < 4; ++nf) atomicAdd(&orow[nf * 16], wgt * acc[m][nf][r]);
        }
      }
    }
  }
}

extern "C" void kernel_launch(void* const* d_in, const int* in_sizes, int n_in,
                              void* d_out, int out_size, void* d_ws, size_t ws_size,
                              hipStream_t stream) {
  const float* hidden = (const float*)d_in[0];  // [2048][1024] f32
  const float* rw = (const float*)d_in[1];      // [1024][16]   f32
  const float* wgu = (const float*)d_in[2];     // [16][1024][2048] f32
  const float* wd = (const float*)d_in[3];      // [16][1024][1024] f32
  float* out = (float*)d_out;                   // [2048][1024] f32
  char* ws = (char*)d_ws;

  // workspace layout (~25 MB)
  int* counts = (int*)(ws);                        // 64 B
  int* offsets = (int*)(ws + 256);                 // 64 B
  int* routing_e = (int*)(ws + 1024);              // 16 KB
  float* routing_w = (float*)(ws + 17408);         // 16 KB
  int* token_of_slot = (int*)(ws + 33792);         // 16 KB
  float* slot_w = (float*)(ws + 50176);            // 16 KB
  float* rwT = (float*)(ws + 65536);               // 64 KB [16][1024] f32
  u16* Xh = (u16*)(ws + 131072ull);                // 4 MB  [2048][1024] bf16 hi
  u16* Xl = (u16*)(ws + 4325376ull);               // 4 MB  bf16 lo residual
  u16* act_h = (u16*)(ws + 8519680ull);            // 8 MB  [4096][1024] bf16 hi
  u16* act_l = (u16*)(ws + 16908288ull);           // 8 MB  bf16 lo residual

  hipMemsetAsync(counts, 0, 64, stream);
  hipMemsetAsync(out, 0, (size_t)out_size * sizeof(float), stream);
  rw_transpose_kernel<<<dim3(64), dim3(256), 0, stream>>>(rw, rwT);
  router_kernel<<<dim3(T_TOK / 4), dim3(256), 0, stream>>>(hidden, rwT, counts, routing_e,
                                                           routing_w);
  scatter_kernel<<<dim3(1), dim3(256), 0, stream>>>(counts, offsets, routing_e, routing_w,
                                                    token_of_slot, slot_w);
  prep_x<<<dim3(T_TOK * H_DIM / 8 / 256), dim3(256), 0, stream>>>(hidden, Xh, Xl);
  moe_gemm1<<<dim3(16, 16), dim3(512), 0, stream>>>(Xh, Xl, wgu, token_of_slot, counts,
                                                    offsets, act_h, act_l);
  moe_gemm2<<<dim3(16, 16), dim3(512), 0, stream>>>(act_h, act_l, wd, token_of_slot,
                                                    slot_w, counts, offsets, out);
}